// Round 4
// baseline (296.625 us; speedup 1.0000x reference)
//
#include <hip/hip_runtime.h>
#include <hip/hip_fp16.h>
#include <math.h>

// 2D inverse DFT (+i sign, 1/512^2 scale) of 64 x 512 x 512 complex, then |.|.
// Register-resident 512-pt FFT per wave: 8 complex/lane (i = k*64 + lane).
// Pass 1 FFTs columns, scales by 1/512, stores DE-REVERSED as fp16 into a
// transposed workspace ws_h[b][x][f] (f natural). Pass 2 FFTs along X,
// applies the second 1/512 + |.|.
//
// Structure (validated correct R2/R3): grid = (64,16), each block loops over
// 4 batches with register-staged prefetch — next tile's global loads issue
// before the current FFT so HBM stays fed during compute.
//
// Launch-bounds history (this HIP build uses CUDA semantics: 2nd arg =
// BLOCKS/CU):
//   (512,8) -> 16 waves/SIMD target -> VGPR clamped to 32 -> massive scratch
//             spill (FETCH 131->417 MB), 3x slower.  [R2]
//   (512)   -> natural alloc = 68 VGPR, 4 over the 64-reg cliff -> only
//             2 blocks/CU resident, occupancy 17.6%, 87 us.  [R3]
//   (512,4) -> 4 blocks/CU = 8 waves/SIMD -> cap exactly 64 VGPR; compiler
//             remats ~4 regs of address math, no spill. Full residency +
//             prefetch overlap.  [R4, this version]

#define TWO_PI_F 6.283185307179586f

__device__ __forceinline__ float2 cmul(float2 a, float2 b) {
    return make_float2(a.x * b.x - a.y * b.y, a.x * b.y + a.y * b.x);
}
__device__ __forceinline__ float2 cadd(float2 a, float2 b) { return make_float2(a.x + b.x, a.y + b.y); }
__device__ __forceinline__ float2 csub(float2 a, float2 b) { return make_float2(a.x - b.x, a.y - b.y); }
__device__ __forceinline__ float2 csq(float2 a) { return make_float2(a.x * a.x - a.y * a.y, 2.f * a.x * a.y); }
__device__ __forceinline__ unsigned rev6(unsigned v) { return __brev(v) >> 26; }

// In-place 512-pt inverse-sign DIF FFT. Lane l, regs k: element i = k*64 + l.
// On exit, position i holds X[rev9(i)]. A = exp(+2*pi*i*l/512).
// (validated vs reference)
__device__ __forceinline__ void fft512(float2* r, float2 A, int l) {
    const float S = 0.70710678118654752f;
    {   // stage d=256: pairs (k, k+4); w = A * exp(2*pi*i*k/8)
        float2 t0 = A;
        float2 t1 = cmul(A, make_float2(S, S));
        float2 t2 = make_float2(-A.y, A.x);
        float2 t3 = cmul(A, make_float2(-S, S));
        float2 u, v;
        u = r[0]; v = r[4]; r[0] = cadd(u, v); r[4] = cmul(csub(u, v), t0);
        u = r[1]; v = r[5]; r[1] = cadd(u, v); r[5] = cmul(csub(u, v), t1);
        u = r[2]; v = r[6]; r[2] = cadd(u, v); r[6] = cmul(csub(u, v), t2);
        u = r[3]; v = r[7]; r[3] = cadd(u, v); r[7] = cmul(csub(u, v), t3);
    }
    float2 A2 = csq(A);
    {   // stage d=128: pairs (k, k+2); w = A^2 * {1, i}
        float2 A2i = make_float2(-A2.y, A2.x);
        float2 u, v;
        u = r[0]; v = r[2]; r[0] = cadd(u, v); r[2] = cmul(csub(u, v), A2);
        u = r[1]; v = r[3]; r[1] = cadd(u, v); r[3] = cmul(csub(u, v), A2i);
        u = r[4]; v = r[6]; r[4] = cadd(u, v); r[6] = cmul(csub(u, v), A2);
        u = r[5]; v = r[7]; r[5] = cadd(u, v); r[7] = cmul(csub(u, v), A2i);
    }
    float2 A4 = csq(A2);
    {   // stage d=64: pairs (k, k+1); w = A^4
        float2 u, v;
        u = r[0]; v = r[1]; r[0] = cadd(u, v); r[1] = cmul(csub(u, v), A4);
        u = r[2]; v = r[3]; r[2] = cadd(u, v); r[3] = cmul(csub(u, v), A4);
        u = r[4]; v = r[5]; r[4] = cadd(u, v); r[5] = cmul(csub(u, v), A4);
        u = r[6]; v = r[7]; r[6] = cadd(u, v); r[7] = cmul(csub(u, v), A4);
    }
    // shuffle stages m = 32,16,8,4,2,1: hi lane: (own-other)*P, P = A^(256/m).
    float2 P = csq(A4);  // A^8
    #pragma unroll
    for (int mi = 0; mi < 6; ++mi) {
        const int m = 32 >> mi;
        const bool hi = (l & m) != 0;
        #pragma unroll
        for (int k = 0; k < 8; ++k) {
            float2 o;
            o.x = __shfl_xor(r[k].x, m);
            o.y = __shfl_xor(r[k].y, m);
            float2 sum = cadd(r[k], o);
            float2 dif = cmul(csub(r[k], o), P);
            r[k].x = hi ? dif.x : sum.x;
            r[k].y = hi ? dif.y : sum.y;
        }
        if (mi < 5) P = csq(P);
    }
}

// Pass 1: IFFT along Y. Block = 512 (8 waves); wave w owns column x0+w.
// grid = (64, 16); each block processes 4 batches b0..b0+3 with prefetch.
__global__ __launch_bounds__(512, 4)
void fft_y_kernel(const float2* __restrict__ in, __half* __restrict__ wsh) {
    __shared__ float2 tile[8 * 512];   // [c][y], y swizzled by 4*(c>>1): 32 KiB
    const int t = threadIdx.x;
    const int w = t >> 6, l = t & 63;
    const int g = t & 3, q = t >> 2;   // staging: x-pair 2g..2g+1, row q
    const int x0 = blockIdx.x * 8;
    const int b0 = blockIdx.y * 4;

    float sA, cA;
    sincosf(TWO_PI_F * (float)l * (1.0f / 512.0f), &sA, &cA);
    const float2 Atw = make_float2(cA, sA);
    const int sw = 4 * (w >> 1);
    const float s = 1.0f / 512.0f;

    // prologue: stage tile for b0 into registers
    float4 v0, v1, v2, v3;
    {
        const float2* src = in + ((size_t)b0 << 18) + x0;
        v0 = *(const float4*)(src + ((size_t)(0 * 128 + q) << 9) + 2 * g);
        v1 = *(const float4*)(src + ((size_t)(1 * 128 + q) << 9) + 2 * g);
        v2 = *(const float4*)(src + ((size_t)(2 * 128 + q) << 9) + 2 * g);
        v3 = *(const float4*)(src + ((size_t)(3 * 128 + q) << 9) + 2 * g);
    }

    for (int tt = 0; tt < 4; ++tt) {
        // write staged regs into the transposed LDS tile
        {
            int ys;
            ys = (0 * 128 + q) ^ (4 * g);
            tile[(2 * g) * 512 + ys]     = make_float2(v0.x, v0.y);
            tile[(2 * g + 1) * 512 + ys] = make_float2(v0.z, v0.w);
            ys = (1 * 128 + q) ^ (4 * g);
            tile[(2 * g) * 512 + ys]     = make_float2(v1.x, v1.y);
            tile[(2 * g + 1) * 512 + ys] = make_float2(v1.z, v1.w);
            ys = (2 * 128 + q) ^ (4 * g);
            tile[(2 * g) * 512 + ys]     = make_float2(v2.x, v2.y);
            tile[(2 * g + 1) * 512 + ys] = make_float2(v2.z, v2.w);
            ys = (3 * 128 + q) ^ (4 * g);
            tile[(2 * g) * 512 + ys]     = make_float2(v3.x, v3.y);
            tile[(2 * g + 1) * 512 + ys] = make_float2(v3.z, v3.w);
        }
        // issue next tile's loads now; they fly during this tile's FFT
        if (tt < 3) {
            const float2* src = in + ((size_t)(b0 + tt + 1) << 18) + x0;
            v0 = *(const float4*)(src + ((size_t)(0 * 128 + q) << 9) + 2 * g);
            v1 = *(const float4*)(src + ((size_t)(1 * 128 + q) << 9) + 2 * g);
            v2 = *(const float4*)(src + ((size_t)(2 * 128 + q) << 9) + 2 * g);
            v3 = *(const float4*)(src + ((size_t)(3 * 128 + q) << 9) + 2 * g);
        }
        __syncthreads();

        float2 r[8];
        #pragma unroll
        for (int k = 0; k < 8; ++k)
            r[k] = tile[w * 512 + ((k * 64 + l) ^ sw)];

        fft512(r, Atw, l);

        // r[k] = Y-freq rev6(l)*8 + rev3(k) of column x = x0+w. De-reverse in
        // addressing; reg order for natural f: 0,4,2,6,1,5,3,7. Scale by 1/512.
        __half* dst = wsh + (((size_t)((b0 + tt) * 512 + x0 + w)) << 10) + rev6((unsigned)l) * 16;
        union { uint4 u; __half2 h[4]; } a0, a1;
        a0.h[0] = __floats2half2_rn(r[0].x * s, r[0].y * s);
        a0.h[1] = __floats2half2_rn(r[4].x * s, r[4].y * s);
        a0.h[2] = __floats2half2_rn(r[2].x * s, r[2].y * s);
        a0.h[3] = __floats2half2_rn(r[6].x * s, r[6].y * s);
        a1.h[0] = __floats2half2_rn(r[1].x * s, r[1].y * s);
        a1.h[1] = __floats2half2_rn(r[5].x * s, r[5].y * s);
        a1.h[2] = __floats2half2_rn(r[3].x * s, r[3].y * s);
        a1.h[3] = __floats2half2_rn(r[7].x * s, r[7].y * s);
        *(uint4*)dst       = a0.u;
        *(uint4*)(dst + 8) = a1.u;

        __syncthreads();   // LDS reads done before next iter's writes
    }
}

// Pass 2: IFFT along X per f-row + magnitude. Block = 512 (8 waves);
// wave w owns row f0+w. grid = (64, 16); 4 batches/block with prefetch.
__global__ __launch_bounds__(512, 4)
void fft_x_mag_kernel(const __half* __restrict__ wsh, float* __restrict__ out) {
    __shared__ uint tile[8 * 512];     // tile[j*512+x] = half2 cplx (x, f0+j): 16 KiB
    const int t = threadIdx.x;
    const int w = t >> 6, l = t & 63;
    const int f0 = blockIdx.x * 8;
    const int b0 = blockIdx.y * 4;

    float sA, cA;
    sincosf(TWO_PI_F * (float)l * (1.0f / 512.0f), &sA, &cA);
    const float2 Atw = make_float2(cA, sA);
    const float s = 1.0f / 512.0f;   // second half of 1/512^2

    // prologue: thread t owns x = t; its 8-f chunk is 32 B contiguous.
    uint4 ua, ub;
    {
        const __half* src = wsh + ((size_t)b0 << 19) + ((size_t)t << 10) + f0 * 2;
        ua = *(const uint4*)(src);
        ub = *(const uint4*)(src + 8);
    }

    for (int tt = 0; tt < 4; ++tt) {
        tile[0 * 512 + t] = ua.x;
        tile[1 * 512 + t] = ua.y;
        tile[2 * 512 + t] = ua.z;
        tile[3 * 512 + t] = ua.w;
        tile[4 * 512 + t] = ub.x;
        tile[5 * 512 + t] = ub.y;
        tile[6 * 512 + t] = ub.z;
        tile[7 * 512 + t] = ub.w;
        if (tt < 3) {
            const __half* src = wsh + ((size_t)(b0 + tt + 1) << 19) + ((size_t)t << 10) + f0 * 2;
            ua = *(const uint4*)(src);
            ub = *(const uint4*)(src + 8);
        }
        __syncthreads();

        float2 r[8];
        #pragma unroll
        for (int k = 0; k < 8; ++k) {
            uint p = tile[w * 512 + k * 64 + l];
            r[k] = __half22float2(*(const __half2*)&p);
        }

        fft512(r, Atw, l);

        // X-freq rev9(k*64+l) = rev6(l)*8 + rev3(k): lane owns 8 consecutive xf.
        float m0 = sqrtf(r[0].x * r[0].x + r[0].y * r[0].y) * s;  // off 0
        float m1 = sqrtf(r[4].x * r[4].x + r[4].y * r[4].y) * s;  // off 1
        float m2 = sqrtf(r[2].x * r[2].x + r[2].y * r[2].y) * s;  // off 2
        float m3 = sqrtf(r[6].x * r[6].x + r[6].y * r[6].y) * s;  // off 3
        float m4 = sqrtf(r[1].x * r[1].x + r[1].y * r[1].y) * s;  // off 4
        float m5 = sqrtf(r[5].x * r[5].x + r[5].y * r[5].y) * s;  // off 5
        float m6 = sqrtf(r[3].x * r[3].x + r[3].y * r[3].y) * s;  // off 6
        float m7 = sqrtf(r[7].x * r[7].x + r[7].y * r[7].y) * s;  // off 7

        float* orow = out + (((size_t)((b0 + tt) * 512 + f0 + w)) << 9) + rev6((unsigned)l) * 8;
        *(float4*)(orow + 0) = make_float4(m0, m1, m2, m3);
        *(float4*)(orow + 4) = make_float4(m4, m5, m6, m7);

        __syncthreads();
    }
}

extern "C" void kernel_launch(void* const* d_in, const int* in_sizes, int n_in,
                              void* d_out, int out_size, void* d_ws, size_t ws_size,
                              hipStream_t stream) {
    const float2* in = (const float2*)d_in[0];
    __half* wsh = (__half*)d_ws;   // ws_h[b][x][f] fp16: 64*512*512*4 = 64 MiB
    float* out = (float*)d_out;

    fft_y_kernel<<<dim3(64, 16), 512, 0, stream>>>(in, wsh);
    fft_x_mag_kernel<<<dim3(64, 16), 512, 0, stream>>>(wsh, out);
}

// Round 6
// 274.499 us; speedup vs baseline: 1.0806x; 1.0806x over previous
//
#include <hip/hip_runtime.h>
#include <hip/hip_fp16.h>
#include <math.h>

// 2D inverse DFT (+i sign, 1/512^2 scale) of 64 x 512 x 512 complex, then |.|.
// Register-resident 512-pt FFT per wave: 8 complex/lane (i = k*64 + lane).
// Pass 1 FFTs columns, scales by 1/512, stores DE-REVERSED as fp16 into a
// transposed workspace ws_h[b][x][f] (f natural). Pass 2 FFTs along X,
// applies the second 1/512 + |.|.
//
// R6: same theory as R5 (cross-lane FFT stages off the LDS pipe) but with
// only battle-tested primitives — R5's v_permlane32_swap inline asm is the
// lone untested construct that could explain a container-level failure, so
// m=32 reverts to __shfl_xor. Exchange primitives per stage:
//   m=32 : __shfl_xor (ds_bpermute — must cross 32-lane halves)
//   m=16 : ds_swizzle 0x401F   (LDS pipe, no-vaddr)
//   m=8  : DPP row_ror:8       (VALU)
//   m=4  : ds_swizzle 0x101F   (LDS pipe)
//   m=2  : DPP quad_perm 0x4E  (VALU)
//   m=1  : DPP quad_perm 0xB1  (VALU)
// LDS-pipe issues/thread-tile: 112 -> 64.
// Structure = R0 single-tile (grid (64,64)): R3/R4 proved time is
// insensitive to occupancy/prefetch (17.6/32.6/48% occ -> 87/89/81 us).
// DO NOT add a 2nd __launch_bounds__ arg: this build reads it as blocks/CU
// ((512,8) -> 32-VGPR clamp -> 600 MB scratch spill; (512,4) -> 64-VGPR
// cap -> slight spill; both slower than natural 68-VGPR allocation).

#define TWO_PI_F 6.283185307179586f

__device__ __forceinline__ float2 cmul(float2 a, float2 b) {
    return make_float2(a.x * b.x - a.y * b.y, a.x * b.y + a.y * b.x);
}
__device__ __forceinline__ float2 cadd(float2 a, float2 b) { return make_float2(a.x + b.x, a.y + b.y); }
__device__ __forceinline__ float2 csub(float2 a, float2 b) { return make_float2(a.x - b.x, a.y - b.y); }
__device__ __forceinline__ float2 csq(float2 a) { return make_float2(a.x * a.x - a.y * a.y, 2.f * a.x * a.y); }
__device__ __forceinline__ unsigned rev6(unsigned v) { return __brev(v) >> 26; }

// --- cross-lane exchange primitives ---

// ds_swizzle xor within 32-lane halves (BitMode: offset = (xor<<10) | 0x1F).
template<int IMM>
__device__ __forceinline__ float2 dswz2(float2 v) {
    float2 o;
    o.x = __int_as_float(__builtin_amdgcn_ds_swizzle(__float_as_int(v.x), IMM));
    o.y = __int_as_float(__builtin_amdgcn_ds_swizzle(__float_as_int(v.y), IMM));
    return o;
}
// DPP cross-lane (VALU): quad_perm 0xB1 = xor1, 0x4E = xor2,
// row_ror:8 (0x128) = +8 mod 16 = xor8 within each 16-lane row.
template<int CTRL>
__device__ __forceinline__ float2 dpp2(float2 v) {
    float2 o;
    o.x = __int_as_float(__builtin_amdgcn_mov_dpp(__float_as_int(v.x), CTRL, 0xF, 0xF, true));
    o.y = __int_as_float(__builtin_amdgcn_mov_dpp(__float_as_int(v.y), CTRL, 0xF, 0xF, true));
    return o;
}

// butterfly: r = hi ? (r - o)*P : (r + o)
__device__ __forceinline__ void bf(float2& rk, float2 o, float2 P, bool hi) {
    float2 sum = cadd(rk, o);
    float2 dif = cmul(csub(rk, o), P);
    rk.x = hi ? dif.x : sum.x;
    rk.y = hi ? dif.y : sum.y;
}

// In-place 512-pt inverse-sign DIF FFT. Lane l, regs k: element i = k*64 + l.
// On exit, position i holds X[rev9(i)]. A = exp(+2*pi*i*l/512).
// (math validated vs reference; only exchange primitives changed since)
__device__ __forceinline__ void fft512(float2* r, float2 A, int l) {
    const float S = 0.70710678118654752f;
    {   // stage d=256: pairs (k, k+4); w = A * exp(2*pi*i*k/8)
        float2 t0 = A;
        float2 t1 = cmul(A, make_float2(S, S));
        float2 t2 = make_float2(-A.y, A.x);
        float2 t3 = cmul(A, make_float2(-S, S));
        float2 u, v;
        u = r[0]; v = r[4]; r[0] = cadd(u, v); r[4] = cmul(csub(u, v), t0);
        u = r[1]; v = r[5]; r[1] = cadd(u, v); r[5] = cmul(csub(u, v), t1);
        u = r[2]; v = r[6]; r[2] = cadd(u, v); r[6] = cmul(csub(u, v), t2);
        u = r[3]; v = r[7]; r[3] = cadd(u, v); r[7] = cmul(csub(u, v), t3);
    }
    float2 A2 = csq(A);
    {   // stage d=128: pairs (k, k+2); w = A^2 * {1, i}
        float2 A2i = make_float2(-A2.y, A2.x);
        float2 u, v;
        u = r[0]; v = r[2]; r[0] = cadd(u, v); r[2] = cmul(csub(u, v), A2);
        u = r[1]; v = r[3]; r[1] = cadd(u, v); r[3] = cmul(csub(u, v), A2i);
        u = r[4]; v = r[6]; r[4] = cadd(u, v); r[6] = cmul(csub(u, v), A2);
        u = r[5]; v = r[7]; r[5] = cadd(u, v); r[7] = cmul(csub(u, v), A2i);
    }
    float2 A4 = csq(A2);
    {   // stage d=64: pairs (k, k+1); w = A^4
        float2 u, v;
        u = r[0]; v = r[1]; r[0] = cadd(u, v); r[1] = cmul(csub(u, v), A4);
        u = r[2]; v = r[3]; r[2] = cadd(u, v); r[3] = cmul(csub(u, v), A4);
        u = r[4]; v = r[5]; r[4] = cadd(u, v); r[5] = cmul(csub(u, v), A4);
        u = r[6]; v = r[7]; r[6] = cadd(u, v); r[7] = cmul(csub(u, v), A4);
    }
    // cross-lane stages m = 32,16,8,4,2,1; hi lane: (own-other)*P, P = A^(256/m).
    float2 P = csq(A4);  // A^8
    {   // m=32: __shfl_xor (only stage crossing the 32-lane halves)
        const bool hi = (l & 32) != 0;
        #pragma unroll
        for (int k = 0; k < 8; ++k) {
            float2 o;
            o.x = __shfl_xor(r[k].x, 32);
            o.y = __shfl_xor(r[k].y, 32);
            bf(r[k], o, P, hi);
        }
        P = csq(P);
    }
    {   // m=16: ds_swizzle xor16 (within 32-half)
        const bool hi = (l & 16) != 0;
        #pragma unroll
        for (int k = 0; k < 8; ++k) bf(r[k], dswz2<0x401F>(r[k]), P, hi);
        P = csq(P);
    }
    {   // m=8: DPP row_ror:8 (xor8 within 16-row)
        const bool hi = (l & 8) != 0;
        #pragma unroll
        for (int k = 0; k < 8; ++k) bf(r[k], dpp2<0x128>(r[k]), P, hi);
        P = csq(P);
    }
    {   // m=4: ds_swizzle xor4
        const bool hi = (l & 4) != 0;
        #pragma unroll
        for (int k = 0; k < 8; ++k) bf(r[k], dswz2<0x101F>(r[k]), P, hi);
        P = csq(P);
    }
    {   // m=2: DPP quad_perm [2,3,0,1]
        const bool hi = (l & 2) != 0;
        #pragma unroll
        for (int k = 0; k < 8; ++k) bf(r[k], dpp2<0x4E>(r[k]), P, hi);
        P = csq(P);
    }
    {   // m=1: DPP quad_perm [1,0,3,2]
        const bool hi = (l & 1) != 0;
        #pragma unroll
        for (int k = 0; k < 8; ++k) bf(r[k], dpp2<0xB1>(r[k]), P, hi);
    }
}

// Pass 1: IFFT along Y. Block = 512 (8 waves); wave w owns column x0+w.
// grid = (64, 64). Front: float4 staged loads into transposed tile [c][y].
// Back: scaled fp16 store to ws_h[b][x][f], 32 B contiguous per lane.
__global__ __launch_bounds__(512)
void fft_y_kernel(const float2* __restrict__ in, __half* __restrict__ wsh) {
    __shared__ float2 tile[8 * 512];   // [c][y], y swizzled by 4*(c>>1): 32 KiB
    const int t = threadIdx.x;
    const int w = t >> 6, l = t & 63;
    const int g = t & 3, q = t >> 2;   // staging: x-pair 2g..2g+1, row q
    const int x0 = blockIdx.x * 8;
    const int b  = blockIdx.y;

    const float2* src = in + ((size_t)b << 18) + x0;
    #pragma unroll
    for (int it = 0; it < 4; ++it) {
        const int y = it * 128 + q;
        const float4 v = *(const float4*)(src + ((size_t)y << 9) + 2 * g);
        const int ys = y ^ (4 * g);
        tile[(2 * g) * 512 + ys]     = make_float2(v.x, v.y);
        tile[(2 * g + 1) * 512 + ys] = make_float2(v.z, v.w);
    }
    __syncthreads();

    float sA, cA;
    sincosf(TWO_PI_F * (float)l * (1.0f / 512.0f), &sA, &cA);
    float2 r[8];
    const int sw = 4 * (w >> 1);
    #pragma unroll
    for (int k = 0; k < 8; ++k)
        r[k] = tile[w * 512 + ((k * 64 + l) ^ sw)];

    fft512(r, make_float2(cA, sA), l);

    // r[k] = Y-freq rev6(l)*8 + rev3(k) of column x = x0+w. De-reverse in
    // addressing; reg order for natural f: 0,4,2,6,1,5,3,7. Scale by 1/512.
    const float s = 1.0f / 512.0f;
    __half* dst = wsh + (((size_t)(b * 512 + x0 + w)) << 10) + rev6((unsigned)l) * 16;
    union { uint4 u; __half2 h[4]; } a0, a1;
    a0.h[0] = __floats2half2_rn(r[0].x * s, r[0].y * s);
    a0.h[1] = __floats2half2_rn(r[4].x * s, r[4].y * s);
    a0.h[2] = __floats2half2_rn(r[2].x * s, r[2].y * s);
    a0.h[3] = __floats2half2_rn(r[6].x * s, r[6].y * s);
    a1.h[0] = __floats2half2_rn(r[1].x * s, r[1].y * s);
    a1.h[1] = __floats2half2_rn(r[5].x * s, r[5].y * s);
    a1.h[2] = __floats2half2_rn(r[3].x * s, r[3].y * s);
    a1.h[3] = __floats2half2_rn(r[7].x * s, r[7].y * s);
    *(uint4*)dst       = a0.u;
    *(uint4*)(dst + 8) = a1.u;
}

// Pass 2: IFFT along X per f-row + magnitude. Block = 512 (8 waves);
// wave w owns row f0+w. grid = (64, 64). fp16 LDS tile, conflict-free.
__global__ __launch_bounds__(512)
void fft_x_mag_kernel(const __half* __restrict__ wsh, float* __restrict__ out) {
    __shared__ uint tile[8 * 512];     // tile[j*512+x] = half2 cplx (x, f0+j): 16 KiB
    const int t = threadIdx.x;
    const int w = t >> 6, l = t & 63;
    const int f0 = blockIdx.x * 8;
    const int b  = blockIdx.y;

    // staging: thread t owns x = t; its 8-f chunk is 32 B contiguous.
    {
        const __half* src = wsh + ((size_t)b << 19) + ((size_t)t << 10) + f0 * 2;
        const uint4 ua = *(const uint4*)(src);
        const uint4 ub = *(const uint4*)(src + 8);
        tile[0 * 512 + t] = ua.x;
        tile[1 * 512 + t] = ua.y;
        tile[2 * 512 + t] = ua.z;
        tile[3 * 512 + t] = ua.w;
        tile[4 * 512 + t] = ub.x;
        tile[5 * 512 + t] = ub.y;
        tile[6 * 512 + t] = ub.z;
        tile[7 * 512 + t] = ub.w;
    }
    __syncthreads();

    float sA, cA;
    sincosf(TWO_PI_F * (float)l * (1.0f / 512.0f), &sA, &cA);
    float2 r[8];
    #pragma unroll
    for (int k = 0; k < 8; ++k) {
        uint p = tile[w * 512 + k * 64 + l];
        r[k] = __half22float2(*(const __half2*)&p);
    }

    fft512(r, make_float2(cA, sA), l);

    const float s = 1.0f / 512.0f;   // second half of 1/512^2
    // X-freq rev9(k*64+l) = rev6(l)*8 + rev3(k): lane owns 8 consecutive xf.
    float m0 = sqrtf(r[0].x * r[0].x + r[0].y * r[0].y) * s;  // off 0
    float m1 = sqrtf(r[4].x * r[4].x + r[4].y * r[4].y) * s;  // off 1
    float m2 = sqrtf(r[2].x * r[2].x + r[2].y * r[2].y) * s;  // off 2
    float m3 = sqrtf(r[6].x * r[6].x + r[6].y * r[6].y) * s;  // off 3
    float m4 = sqrtf(r[1].x * r[1].x + r[1].y * r[1].y) * s;  // off 4
    float m5 = sqrtf(r[5].x * r[5].x + r[5].y * r[5].y) * s;  // off 5
    float m6 = sqrtf(r[3].x * r[3].x + r[3].y * r[3].y) * s;  // off 6
    float m7 = sqrtf(r[7].x * r[7].x + r[7].y * r[7].y) * s;  // off 7

    float* orow = out + (((size_t)(b * 512 + f0 + w)) << 9) + rev6((unsigned)l) * 8;
    *(float4*)(orow + 0) = make_float4(m0, m1, m2, m3);
    *(float4*)(orow + 4) = make_float4(m4, m5, m6, m7);
}

extern "C" void kernel_launch(void* const* d_in, const int* in_sizes, int n_in,
                              void* d_out, int out_size, void* d_ws, size_t ws_size,
                              hipStream_t stream) {
    const float2* in = (const float2*)d_in[0];
    __half* wsh = (__half*)d_ws;   // ws_h[b][x][f] fp16: 64*512*512*4 = 64 MiB
    float* out = (float*)d_out;

    fft_y_kernel<<<dim3(64, 64), 512, 0, stream>>>(in, wsh);
    fft_x_mag_kernel<<<dim3(64, 64), 512, 0, stream>>>(wsh, out);
}

// Round 7
// 273.103 us; speedup vs baseline: 1.0861x; 1.0051x over previous
//
#include <hip/hip_runtime.h>
#include <hip/hip_fp16.h>
#include <math.h>

// 2D inverse DFT (+i sign, 1/512^2 scale) of 64 x 512 x 512 complex, then |.|.
// Register-resident 512-pt FFT per wave: 8 complex/lane (i = k*64 + lane).
// Pass 1 FFTs columns, scales by 1/512, stores DE-REVERSED as fp16 into a
// transposed workspace ws_h[b][x][f] (f natural). Pass 2 FFTs along X,
// applies the second 1/512 + |.|.
//
// R7: VALU-throughput attack (evidence: dur insensitive to occupancy 48->17.6%
// (+7%), to prefetch, and to LDS-pipe mix (R6); FETCH/WRITE at algorithmic
// min; => VALU-bound, with the gfx94x-fallback VALUBusy formula reading ~42%
// for a ~84%-busy wave64 2-cyc/op pipe).
//  - butterfly: (r+-o) select + hi-only cmul (10 VALU) replaced by
//    pre = r + sgn*o (2 fma) then cmul(pre, T) (4), sgn/T hoisted per stage.
//    BIT-EXACT: lo computes (r+o)*1 - y*0, hi computes (r-o)*P as before.
//    48 butterflies: -156 VALU/thread.
//  - sincosf (libm, ~50 ops) -> raw v_sin/cos_f32 (ISA input is REVOLUTIONS;
//    arg l/512 is already the revolution count, in [0,0.124) -- no reduction).
// Exchange primitives kept from R6 (passed): m=32 shfl_xor, m=16/4 ds_swizzle,
// m=8/2/1 DPP.
// DO NOT add a 2nd __launch_bounds__ arg: this build reads it as blocks/CU
// ((512,8) -> 32-VGPR clamp -> 600 MB scratch spill; (512,4) -> 64-VGPR
// cap -> slight spill; both slower than natural allocation).

#define TWO_PI_F 6.283185307179586f

__device__ __forceinline__ float2 cmul(float2 a, float2 b) {
    return make_float2(a.x * b.x - a.y * b.y, a.x * b.y + a.y * b.x);
}
__device__ __forceinline__ float2 cadd(float2 a, float2 b) { return make_float2(a.x + b.x, a.y + b.y); }
__device__ __forceinline__ float2 csub(float2 a, float2 b) { return make_float2(a.x - b.x, a.y - b.y); }
__device__ __forceinline__ float2 csq(float2 a) { return make_float2(a.x * a.x - a.y * a.y, 2.f * a.x * a.y); }
__device__ __forceinline__ unsigned rev6(unsigned v) { return __brev(v) >> 26; }

// --- cross-lane exchange primitives ---

// ds_swizzle xor within 32-lane halves (BitMode: offset = (xor<<10) | 0x1F).
template<int IMM>
__device__ __forceinline__ float2 dswz2(float2 v) {
    float2 o;
    o.x = __int_as_float(__builtin_amdgcn_ds_swizzle(__float_as_int(v.x), IMM));
    o.y = __int_as_float(__builtin_amdgcn_ds_swizzle(__float_as_int(v.y), IMM));
    return o;
}
// DPP cross-lane (VALU): quad_perm 0xB1 = xor1, 0x4E = xor2,
// row_ror:8 (0x128) = +8 mod 16 = xor8 within each 16-lane row.
template<int CTRL>
__device__ __forceinline__ float2 dpp2(float2 v) {
    float2 o;
    o.x = __int_as_float(__builtin_amdgcn_mov_dpp(__float_as_int(v.x), CTRL, 0xF, 0xF, true));
    o.y = __int_as_float(__builtin_amdgcn_mov_dpp(__float_as_int(v.y), CTRL, 0xF, 0xF, true));
    return o;
}

// butterfly, 6 VALU: pre = r + sgn*o; r = pre * T.
// lo lanes: sgn=+1, T=(1,0): r = (r+o) exactly (mul by 1, fma with 0).
// hi lanes: sgn=-1, T=P:     r = (r-o)*P — identical math to the old form.
__device__ __forceinline__ void bf2(float2& rk, float2 o, float2 T, float sgn) {
    float2 pre = make_float2(fmaf(sgn, o.x, rk.x), fmaf(sgn, o.y, rk.y));
    rk = cmul(pre, T);
}

// In-place 512-pt inverse-sign DIF FFT. Lane l, regs k: element i = k*64 + l.
// On exit, position i holds X[rev9(i)]. A = exp(+2*pi*i*l/512).
// (math validated vs reference; exchange prims + butterfly form changed
// bit-exactly since)
__device__ __forceinline__ void fft512(float2* r, float2 A, int l) {
    const float S = 0.70710678118654752f;
    {   // stage d=256: pairs (k, k+4); w = A * exp(2*pi*i*k/8)
        float2 t0 = A;
        float2 t1 = cmul(A, make_float2(S, S));
        float2 t2 = make_float2(-A.y, A.x);
        float2 t3 = cmul(A, make_float2(-S, S));
        float2 u, v;
        u = r[0]; v = r[4]; r[0] = cadd(u, v); r[4] = cmul(csub(u, v), t0);
        u = r[1]; v = r[5]; r[1] = cadd(u, v); r[5] = cmul(csub(u, v), t1);
        u = r[2]; v = r[6]; r[2] = cadd(u, v); r[6] = cmul(csub(u, v), t2);
        u = r[3]; v = r[7]; r[3] = cadd(u, v); r[7] = cmul(csub(u, v), t3);
    }
    float2 A2 = csq(A);
    {   // stage d=128: pairs (k, k+2); w = A^2 * {1, i}
        float2 A2i = make_float2(-A2.y, A2.x);
        float2 u, v;
        u = r[0]; v = r[2]; r[0] = cadd(u, v); r[2] = cmul(csub(u, v), A2);
        u = r[1]; v = r[3]; r[1] = cadd(u, v); r[3] = cmul(csub(u, v), A2i);
        u = r[4]; v = r[6]; r[4] = cadd(u, v); r[6] = cmul(csub(u, v), A2);
        u = r[5]; v = r[7]; r[5] = cadd(u, v); r[7] = cmul(csub(u, v), A2i);
    }
    float2 A4 = csq(A2);
    {   // stage d=64: pairs (k, k+1); w = A^4
        float2 u, v;
        u = r[0]; v = r[1]; r[0] = cadd(u, v); r[1] = cmul(csub(u, v), A4);
        u = r[2]; v = r[3]; r[2] = cadd(u, v); r[3] = cmul(csub(u, v), A4);
        u = r[4]; v = r[5]; r[4] = cadd(u, v); r[5] = cmul(csub(u, v), A4);
        u = r[6]; v = r[7]; r[6] = cadd(u, v); r[7] = cmul(csub(u, v), A4);
    }
    // cross-lane stages m = 32,16,8,4,2,1; hi lane: (own-other)*P, P = A^(256/m).
    const float2 ONE = make_float2(1.0f, 0.0f);
    float2 P = csq(A4);  // A^8
    {   // m=32: __shfl_xor (only stage crossing the 32-lane halves)
        const bool hi = (l & 32) != 0;
        const float sgn = hi ? -1.0f : 1.0f;
        const float2 T = hi ? P : ONE;
        #pragma unroll
        for (int k = 0; k < 8; ++k) {
            float2 o;
            o.x = __shfl_xor(r[k].x, 32);
            o.y = __shfl_xor(r[k].y, 32);
            bf2(r[k], o, T, sgn);
        }
        P = csq(P);
    }
    {   // m=16: ds_swizzle xor16 (within 32-half)
        const bool hi = (l & 16) != 0;
        const float sgn = hi ? -1.0f : 1.0f;
        const float2 T = hi ? P : ONE;
        #pragma unroll
        for (int k = 0; k < 8; ++k) bf2(r[k], dswz2<0x401F>(r[k]), T, sgn);
        P = csq(P);
    }
    {   // m=8: DPP row_ror:8 (xor8 within 16-row)
        const bool hi = (l & 8) != 0;
        const float sgn = hi ? -1.0f : 1.0f;
        const float2 T = hi ? P : ONE;
        #pragma unroll
        for (int k = 0; k < 8; ++k) bf2(r[k], dpp2<0x128>(r[k]), T, sgn);
        P = csq(P);
    }
    {   // m=4: ds_swizzle xor4
        const bool hi = (l & 4) != 0;
        const float sgn = hi ? -1.0f : 1.0f;
        const float2 T = hi ? P : ONE;
        #pragma unroll
        for (int k = 0; k < 8; ++k) bf2(r[k], dswz2<0x101F>(r[k]), T, sgn);
        P = csq(P);
    }
    {   // m=2: DPP quad_perm [2,3,0,1]
        const bool hi = (l & 2) != 0;
        const float sgn = hi ? -1.0f : 1.0f;
        const float2 T = hi ? P : ONE;
        #pragma unroll
        for (int k = 0; k < 8; ++k) bf2(r[k], dpp2<0x4E>(r[k]), T, sgn);
        P = csq(P);
    }
    {   // m=1: DPP quad_perm [1,0,3,2]
        const bool hi = (l & 1) != 0;
        const float sgn = hi ? -1.0f : 1.0f;
        const float2 T = hi ? P : ONE;
        #pragma unroll
        for (int k = 0; k < 8; ++k) bf2(r[k], dpp2<0xB1>(r[k]), T, sgn);
    }
}

// twiddle A = exp(+2*pi*i*l/512) via raw v_sin/cos_f32 (input in REVOLUTIONS;
// l/512 in [0, 0.124) needs no range reduction).
__device__ __forceinline__ float2 twiddleA(int l) {
    const float rev = (float)l * (1.0f / 512.0f);
    return make_float2(__builtin_amdgcn_cosf(rev), __builtin_amdgcn_sinf(rev));
}

// Pass 1: IFFT along Y. Block = 512 (8 waves); wave w owns column x0+w.
// grid = (64, 64). Front: float4 staged loads into transposed tile [c][y].
// Back: scaled fp16 store to ws_h[b][x][f], 32 B contiguous per lane.
__global__ __launch_bounds__(512)
void fft_y_kernel(const float2* __restrict__ in, __half* __restrict__ wsh) {
    __shared__ float2 tile[8 * 512];   // [c][y], y swizzled by 4*(c>>1): 32 KiB
    const int t = threadIdx.x;
    const int w = t >> 6, l = t & 63;
    const int g = t & 3, q = t >> 2;   // staging: x-pair 2g..2g+1, row q
    const int x0 = blockIdx.x * 8;
    const int b  = blockIdx.y;

    const float2* src = in + ((size_t)b << 18) + x0;
    #pragma unroll
    for (int it = 0; it < 4; ++it) {
        const int y = it * 128 + q;
        const float4 v = *(const float4*)(src + ((size_t)y << 9) + 2 * g);
        const int ys = y ^ (4 * g);
        tile[(2 * g) * 512 + ys]     = make_float2(v.x, v.y);
        tile[(2 * g + 1) * 512 + ys] = make_float2(v.z, v.w);
    }
    __syncthreads();

    float2 r[8];
    const int sw = 4 * (w >> 1);
    #pragma unroll
    for (int k = 0; k < 8; ++k)
        r[k] = tile[w * 512 + ((k * 64 + l) ^ sw)];

    fft512(r, twiddleA(l), l);

    // r[k] = Y-freq rev6(l)*8 + rev3(k) of column x = x0+w. De-reverse in
    // addressing; reg order for natural f: 0,4,2,6,1,5,3,7. Scale by 1/512.
    const float s = 1.0f / 512.0f;
    __half* dst = wsh + (((size_t)(b * 512 + x0 + w)) << 10) + rev6((unsigned)l) * 16;
    union { uint4 u; __half2 h[4]; } a0, a1;
    a0.h[0] = __floats2half2_rn(r[0].x * s, r[0].y * s);
    a0.h[1] = __floats2half2_rn(r[4].x * s, r[4].y * s);
    a0.h[2] = __floats2half2_rn(r[2].x * s, r[2].y * s);
    a0.h[3] = __floats2half2_rn(r[6].x * s, r[6].y * s);
    a1.h[0] = __floats2half2_rn(r[1].x * s, r[1].y * s);
    a1.h[1] = __floats2half2_rn(r[5].x * s, r[5].y * s);
    a1.h[2] = __floats2half2_rn(r[3].x * s, r[3].y * s);
    a1.h[3] = __floats2half2_rn(r[7].x * s, r[7].y * s);
    *(uint4*)dst       = a0.u;
    *(uint4*)(dst + 8) = a1.u;
}

// Pass 2: IFFT along X per f-row + magnitude. Block = 512 (8 waves);
// wave w owns row f0+w. grid = (64, 64). fp16 LDS tile, conflict-free.
__global__ __launch_bounds__(512)
void fft_x_mag_kernel(const __half* __restrict__ wsh, float* __restrict__ out) {
    __shared__ uint tile[8 * 512];     // tile[j*512+x] = half2 cplx (x, f0+j): 16 KiB
    const int t = threadIdx.x;
    const int w = t >> 6, l = t & 63;
    const int f0 = blockIdx.x * 8;
    const int b  = blockIdx.y;

    // staging: thread t owns x = t; its 8-f chunk is 32 B contiguous.
    {
        const __half* src = wsh + ((size_t)b << 19) + ((size_t)t << 10) + f0 * 2;
        const uint4 ua = *(const uint4*)(src);
        const uint4 ub = *(const uint4*)(src + 8);
        tile[0 * 512 + t] = ua.x;
        tile[1 * 512 + t] = ua.y;
        tile[2 * 512 + t] = ua.z;
        tile[3 * 512 + t] = ua.w;
        tile[4 * 512 + t] = ub.x;
        tile[5 * 512 + t] = ub.y;
        tile[6 * 512 + t] = ub.z;
        tile[7 * 512 + t] = ub.w;
    }
    __syncthreads();

    float2 r[8];
    #pragma unroll
    for (int k = 0; k < 8; ++k) {
        uint p = tile[w * 512 + k * 64 + l];
        r[k] = __half22float2(*(const __half2*)&p);
    }

    fft512(r, twiddleA(l), l);

    const float s = 1.0f / 512.0f;   // second half of 1/512^2
    // X-freq rev9(k*64+l) = rev6(l)*8 + rev3(k): lane owns 8 consecutive xf.
    float m0 = sqrtf(r[0].x * r[0].x + r[0].y * r[0].y) * s;  // off 0
    float m1 = sqrtf(r[4].x * r[4].x + r[4].y * r[4].y) * s;  // off 1
    float m2 = sqrtf(r[2].x * r[2].x + r[2].y * r[2].y) * s;  // off 2
    float m3 = sqrtf(r[6].x * r[6].x + r[6].y * r[6].y) * s;  // off 3
    float m4 = sqrtf(r[1].x * r[1].x + r[1].y * r[1].y) * s;  // off 4
    float m5 = sqrtf(r[5].x * r[5].x + r[5].y * r[5].y) * s;  // off 5
    float m6 = sqrtf(r[3].x * r[3].x + r[3].y * r[3].y) * s;  // off 6
    float m7 = sqrtf(r[7].x * r[7].x + r[7].y * r[7].y) * s;  // off 7

    float* orow = out + (((size_t)(b * 512 + f0 + w)) << 9) + rev6((unsigned)l) * 8;
    *(float4*)(orow + 0) = make_float4(m0, m1, m2, m3);
    *(float4*)(orow + 4) = make_float4(m4, m5, m6, m7);
}

extern "C" void kernel_launch(void* const* d_in, const int* in_sizes, int n_in,
                              void* d_out, int out_size, void* d_ws, size_t ws_size,
                              hipStream_t stream) {
    const float2* in = (const float2*)d_in[0];
    __half* wsh = (__half*)d_ws;   // ws_h[b][x][f] fp16: 64*512*512*4 = 64 MiB
    float* out = (float*)d_out;

    fft_y_kernel<<<dim3(64, 64), 512, 0, stream>>>(in, wsh);
    fft_x_mag_kernel<<<dim3(64, 64), 512, 0, stream>>>(wsh, out);
}

// Round 8
// 260.786 us; speedup vs baseline: 1.1374x; 1.0472x over previous
//
#include <hip/hip_runtime.h>
#include <hip/hip_fp16.h>
#include <math.h>

// 2D inverse DFT (+i sign, 1/512^2 scale) of 64 x 512 x 512 complex, then |.|.
// Register-resident 512-pt FFT per wave: 8 complex/lane (i = k*64 + lane).
// Pass 1 FFTs columns, scales by 1/512, stores DE-REVERSED as fp16 into the
// workspace. Pass 2 FFTs along X, applies the second 1/512 + |.|.
//
// R8: workspace layout change ws[b][x][f] -> ws[b][j=f>>3][x][fi=f&7].
// Old layout: pass-2 lane read 32 B at 2 KB stride; each 128 B line held
// f-chunks of FOUR different blocks (f0,f0+8,+16,+24) -> round-robin XCD
// dispatch splits the line across 4 private L2s -> up to 4x HBM/L3 read
// amplification for pass 2 (67 -> ~268 MB), matching fft_x ~70 us.
// New layout: pass-2 block j reads one contiguous 16 KB slab (32 B/lane,
// lane-consecutive). Pass-1 writes scatter per-wave, but each 128 B line is
// completed by 4 waves of the SAME block (x0..x0+3 / +4..+7) on one L2 ->
// full-line write-combining, WRITE_SIZE unchanged.
// FFT internals (R7, passed): bf2 butterflies (bit-exact fma form),
// raw v_sin/cos twiddles, m=32 shfl_xor, m=16/4 ds_swizzle, m=8/2/1 DPP.
// DO NOT add a 2nd __launch_bounds__ arg: this build reads it as blocks/CU
// ((512,8) -> 32-VGPR clamp -> 600 MB scratch spill; (512,4) -> 64-VGPR
// cap -> slight spill; both slower than natural allocation).

#define TWO_PI_F 6.283185307179586f

__device__ __forceinline__ float2 cmul(float2 a, float2 b) {
    return make_float2(a.x * b.x - a.y * b.y, a.x * b.y + a.y * b.x);
}
__device__ __forceinline__ float2 cadd(float2 a, float2 b) { return make_float2(a.x + b.x, a.y + b.y); }
__device__ __forceinline__ float2 csub(float2 a, float2 b) { return make_float2(a.x - b.x, a.y - b.y); }
__device__ __forceinline__ float2 csq(float2 a) { return make_float2(a.x * a.x - a.y * a.y, 2.f * a.x * a.y); }
__device__ __forceinline__ unsigned rev6(unsigned v) { return __brev(v) >> 26; }

// --- cross-lane exchange primitives ---

// ds_swizzle xor within 32-lane halves (BitMode: offset = (xor<<10) | 0x1F).
template<int IMM>
__device__ __forceinline__ float2 dswz2(float2 v) {
    float2 o;
    o.x = __int_as_float(__builtin_amdgcn_ds_swizzle(__float_as_int(v.x), IMM));
    o.y = __int_as_float(__builtin_amdgcn_ds_swizzle(__float_as_int(v.y), IMM));
    return o;
}
// DPP cross-lane (VALU): quad_perm 0xB1 = xor1, 0x4E = xor2,
// row_ror:8 (0x128) = +8 mod 16 = xor8 within each 16-lane row.
template<int CTRL>
__device__ __forceinline__ float2 dpp2(float2 v) {
    float2 o;
    o.x = __int_as_float(__builtin_amdgcn_mov_dpp(__float_as_int(v.x), CTRL, 0xF, 0xF, true));
    o.y = __int_as_float(__builtin_amdgcn_mov_dpp(__float_as_int(v.y), CTRL, 0xF, 0xF, true));
    return o;
}

// butterfly, 6 VALU: pre = r + sgn*o; r = pre * T.
// lo lanes: sgn=+1, T=(1,0): r = (r+o) exactly. hi lanes: sgn=-1, T=P.
__device__ __forceinline__ void bf2(float2& rk, float2 o, float2 T, float sgn) {
    float2 pre = make_float2(fmaf(sgn, o.x, rk.x), fmaf(sgn, o.y, rk.y));
    rk = cmul(pre, T);
}

// In-place 512-pt inverse-sign DIF FFT. Lane l, regs k: element i = k*64 + l.
// On exit, position i holds X[rev9(i)]. A = exp(+2*pi*i*l/512).
__device__ __forceinline__ void fft512(float2* r, float2 A, int l) {
    const float S = 0.70710678118654752f;
    {   // stage d=256: pairs (k, k+4); w = A * exp(2*pi*i*k/8)
        float2 t0 = A;
        float2 t1 = cmul(A, make_float2(S, S));
        float2 t2 = make_float2(-A.y, A.x);
        float2 t3 = cmul(A, make_float2(-S, S));
        float2 u, v;
        u = r[0]; v = r[4]; r[0] = cadd(u, v); r[4] = cmul(csub(u, v), t0);
        u = r[1]; v = r[5]; r[1] = cadd(u, v); r[5] = cmul(csub(u, v), t1);
        u = r[2]; v = r[6]; r[2] = cadd(u, v); r[6] = cmul(csub(u, v), t2);
        u = r[3]; v = r[7]; r[3] = cadd(u, v); r[7] = cmul(csub(u, v), t3);
    }
    float2 A2 = csq(A);
    {   // stage d=128: pairs (k, k+2); w = A^2 * {1, i}
        float2 A2i = make_float2(-A2.y, A2.x);
        float2 u, v;
        u = r[0]; v = r[2]; r[0] = cadd(u, v); r[2] = cmul(csub(u, v), A2);
        u = r[1]; v = r[3]; r[1] = cadd(u, v); r[3] = cmul(csub(u, v), A2i);
        u = r[4]; v = r[6]; r[4] = cadd(u, v); r[6] = cmul(csub(u, v), A2);
        u = r[5]; v = r[7]; r[5] = cadd(u, v); r[7] = cmul(csub(u, v), A2i);
    }
    float2 A4 = csq(A2);
    {   // stage d=64: pairs (k, k+1); w = A^4
        float2 u, v;
        u = r[0]; v = r[1]; r[0] = cadd(u, v); r[1] = cmul(csub(u, v), A4);
        u = r[2]; v = r[3]; r[2] = cadd(u, v); r[3] = cmul(csub(u, v), A4);
        u = r[4]; v = r[5]; r[4] = cadd(u, v); r[5] = cmul(csub(u, v), A4);
        u = r[6]; v = r[7]; r[6] = cadd(u, v); r[7] = cmul(csub(u, v), A4);
    }
    // cross-lane stages m = 32,16,8,4,2,1; hi lane: (own-other)*P, P = A^(256/m).
    const float2 ONE = make_float2(1.0f, 0.0f);
    float2 P = csq(A4);  // A^8
    {   // m=32: __shfl_xor (only stage crossing the 32-lane halves)
        const bool hi = (l & 32) != 0;
        const float sgn = hi ? -1.0f : 1.0f;
        const float2 T = hi ? P : ONE;
        #pragma unroll
        for (int k = 0; k < 8; ++k) {
            float2 o;
            o.x = __shfl_xor(r[k].x, 32);
            o.y = __shfl_xor(r[k].y, 32);
            bf2(r[k], o, T, sgn);
        }
        P = csq(P);
    }
    {   // m=16: ds_swizzle xor16 (within 32-half)
        const bool hi = (l & 16) != 0;
        const float sgn = hi ? -1.0f : 1.0f;
        const float2 T = hi ? P : ONE;
        #pragma unroll
        for (int k = 0; k < 8; ++k) bf2(r[k], dswz2<0x401F>(r[k]), T, sgn);
        P = csq(P);
    }
    {   // m=8: DPP row_ror:8 (xor8 within 16-row)
        const bool hi = (l & 8) != 0;
        const float sgn = hi ? -1.0f : 1.0f;
        const float2 T = hi ? P : ONE;
        #pragma unroll
        for (int k = 0; k < 8; ++k) bf2(r[k], dpp2<0x128>(r[k]), T, sgn);
        P = csq(P);
    }
    {   // m=4: ds_swizzle xor4
        const bool hi = (l & 4) != 0;
        const float sgn = hi ? -1.0f : 1.0f;
        const float2 T = hi ? P : ONE;
        #pragma unroll
        for (int k = 0; k < 8; ++k) bf2(r[k], dswz2<0x101F>(r[k]), T, sgn);
        P = csq(P);
    }
    {   // m=2: DPP quad_perm [2,3,0,1]
        const bool hi = (l & 2) != 0;
        const float sgn = hi ? -1.0f : 1.0f;
        const float2 T = hi ? P : ONE;
        #pragma unroll
        for (int k = 0; k < 8; ++k) bf2(r[k], dpp2<0x4E>(r[k]), T, sgn);
        P = csq(P);
    }
    {   // m=1: DPP quad_perm [1,0,3,2]
        const bool hi = (l & 1) != 0;
        const float sgn = hi ? -1.0f : 1.0f;
        const float2 T = hi ? P : ONE;
        #pragma unroll
        for (int k = 0; k < 8; ++k) bf2(r[k], dpp2<0xB1>(r[k]), T, sgn);
    }
}

// twiddle A = exp(+2*pi*i*l/512) via raw v_sin/cos_f32 (input in REVOLUTIONS;
// l/512 in [0, 0.124) needs no range reduction).
__device__ __forceinline__ float2 twiddleA(int l) {
    const float rev = (float)l * (1.0f / 512.0f);
    return make_float2(__builtin_amdgcn_cosf(rev), __builtin_amdgcn_sinf(rev));
}

// Pass 1: IFFT along Y. Block = 512 (8 waves); wave w owns column x0+w.
// grid = (64, 64). Front: float4 staged loads into transposed tile [c][y].
// Back: scaled fp16 store to ws[b][j=rev6(l)][x][fi], 32 B contiguous/lane.
__global__ __launch_bounds__(512)
void fft_y_kernel(const float2* __restrict__ in, __half* __restrict__ wsh) {
    __shared__ float2 tile[8 * 512];   // [c][y], y swizzled by 4*(c>>1): 32 KiB
    const int t = threadIdx.x;
    const int w = t >> 6, l = t & 63;
    const int g = t & 3, q = t >> 2;   // staging: x-pair 2g..2g+1, row q
    const int x0 = blockIdx.x * 8;
    const int b  = blockIdx.y;

    const float2* src = in + ((size_t)b << 18) + x0;
    #pragma unroll
    for (int it = 0; it < 4; ++it) {
        const int y = it * 128 + q;
        const float4 v = *(const float4*)(src + ((size_t)y << 9) + 2 * g);
        const int ys = y ^ (4 * g);
        tile[(2 * g) * 512 + ys]     = make_float2(v.x, v.y);
        tile[(2 * g + 1) * 512 + ys] = make_float2(v.z, v.w);
    }
    __syncthreads();

    float2 r[8];
    const int sw = 4 * (w >> 1);
    #pragma unroll
    for (int k = 0; k < 8; ++k)
        r[k] = tile[w * 512 + ((k * 64 + l) ^ sw)];

    fft512(r, twiddleA(l), l);

    // r[k] = Y-freq rev6(l)*8 + rev3(k) of column x = x0+w. Lane's 8 freqs are
    // f = rev6(l)*8 + {0..7}; under ws[b][j][x][fi] they are one contiguous
    // 32 B chunk at halfs offset (b<<19) + (rev6(l)<<13) + (x<<4).
    const float s = 1.0f / 512.0f;
    __half* dst = wsh + ((size_t)b << 19) + ((size_t)rev6((unsigned)l) << 13)
                      + ((size_t)(x0 + w) << 4);
    union { uint4 u; __half2 h[4]; } a0, a1;
    a0.h[0] = __floats2half2_rn(r[0].x * s, r[0].y * s);
    a0.h[1] = __floats2half2_rn(r[4].x * s, r[4].y * s);
    a0.h[2] = __floats2half2_rn(r[2].x * s, r[2].y * s);
    a0.h[3] = __floats2half2_rn(r[6].x * s, r[6].y * s);
    a1.h[0] = __floats2half2_rn(r[1].x * s, r[1].y * s);
    a1.h[1] = __floats2half2_rn(r[5].x * s, r[5].y * s);
    a1.h[2] = __floats2half2_rn(r[3].x * s, r[3].y * s);
    a1.h[3] = __floats2half2_rn(r[7].x * s, r[7].y * s);
    *(uint4*)dst       = a0.u;
    *(uint4*)(dst + 8) = a1.u;
}

// Pass 2: IFFT along X per f-row + magnitude. Block = 512 (8 waves);
// wave w owns row f0+w. grid = (64, 64). Block j reads its contiguous 16 KiB
// slab ws[b][j][*][*]: thread t gets x = t's 8 fi-chunks (32 B at t*32).
__global__ __launch_bounds__(512)
void fft_x_mag_kernel(const __half* __restrict__ wsh, float* __restrict__ out) {
    __shared__ uint tile[8 * 512];     // tile[fi*512+x] = half2 cplx (x, f0+fi): 16 KiB
    const int t = threadIdx.x;
    const int w = t >> 6, l = t & 63;
    const int j  = blockIdx.x;         // f-octet index; f0 = 8j
    const int f0 = j * 8;
    const int b  = blockIdx.y;

    {
        const __half* src = wsh + ((size_t)b << 19) + ((size_t)j << 13) + ((size_t)t << 4);
        const uint4 ua = *(const uint4*)(src);
        const uint4 ub = *(const uint4*)(src + 8);
        tile[0 * 512 + t] = ua.x;
        tile[1 * 512 + t] = ua.y;
        tile[2 * 512 + t] = ua.z;
        tile[3 * 512 + t] = ua.w;
        tile[4 * 512 + t] = ub.x;
        tile[5 * 512 + t] = ub.y;
        tile[6 * 512 + t] = ub.z;
        tile[7 * 512 + t] = ub.w;
    }
    __syncthreads();

    float2 r[8];
    #pragma unroll
    for (int k = 0; k < 8; ++k) {
        uint p = tile[w * 512 + k * 64 + l];
        r[k] = __half22float2(*(const __half2*)&p);
    }

    fft512(r, twiddleA(l), l);

    const float s = 1.0f / 512.0f;   // second half of 1/512^2
    // X-freq rev9(k*64+l) = rev6(l)*8 + rev3(k): lane owns 8 consecutive xf.
    float m0 = sqrtf(r[0].x * r[0].x + r[0].y * r[0].y) * s;  // off 0
    float m1 = sqrtf(r[4].x * r[4].x + r[4].y * r[4].y) * s;  // off 1
    float m2 = sqrtf(r[2].x * r[2].x + r[2].y * r[2].y) * s;  // off 2
    float m3 = sqrtf(r[6].x * r[6].x + r[6].y * r[6].y) * s;  // off 3
    float m4 = sqrtf(r[1].x * r[1].x + r[1].y * r[1].y) * s;  // off 4
    float m5 = sqrtf(r[5].x * r[5].x + r[5].y * r[5].y) * s;  // off 5
    float m6 = sqrtf(r[3].x * r[3].x + r[3].y * r[3].y) * s;  // off 6
    float m7 = sqrtf(r[7].x * r[7].x + r[7].y * r[7].y) * s;  // off 7

    float* orow = out + (((size_t)(b * 512 + f0 + w)) << 9) + rev6((unsigned)l) * 8;
    *(float4*)(orow + 0) = make_float4(m0, m1, m2, m3);
    *(float4*)(orow + 4) = make_float4(m4, m5, m6, m7);
}

extern "C" void kernel_launch(void* const* d_in, const int* in_sizes, int n_in,
                              void* d_out, int out_size, void* d_ws, size_t ws_size,
                              hipStream_t stream) {
    const float2* in = (const float2*)d_in[0];
    __half* wsh = (__half*)d_ws;   // ws[b][j][x][fi] fp16: 64*64*512*8*4B = 64 MiB
    float* out = (float*)d_out;

    fft_y_kernel<<<dim3(64, 64), 512, 0, stream>>>(in, wsh);
    fft_x_mag_kernel<<<dim3(64, 64), 512, 0, stream>>>(wsh, out);
}